// Round 16
// baseline (110.693 us; speedup 1.0000x reference)
//
#include <hip/hip_runtime.h>

// Problem constants (fixed by setup_inputs): bs=8, m=4096, T=32, E=65536
#define M      4096
#define TT     32
#define BS     8
#define EE     65536
#define NROWS  (BS * M)                   // 32768
#define WPR    128                        // 32-bit words per row bitmap (M/32)
#define NBLK   (NROWS / 16)               // compute grid = 2048 blocks (2 rows/group)

// ws layout: [bitmap 16 MB][partials 8 KB]
// The memset is mandatory: it warms the coherence point for the atomics
// (R12: removing it cost +25us; R14: poison-placement trick cost +23us).
#define BITS_BYTES ((size_t)NROWS * WPR * 4)          // 16 MB
#define PART_BYTES ((size_t)NBLK * 4)                 // 8 KB
#define WS_NEED    (BITS_BYTES + PART_BYTES)

// ---------------- Fast path ----------------

// One edge per thread, ONE non-returning atomicOr per edge. Fire-and-forget:
// no result dependency -> no latency exposure, ~4x the throughput of the
// returning CAS build (R4 evidence: 2M atomicOr ~= 27us aggregate).
// Bitmap gives exact dedup for free.
__global__ __launch_bounds__(256) void build_bits(const int* __restrict__ coo,
                                                  unsigned int* __restrict__ bits) {
    int idx = blockIdx.x * 256 + threadIdx.x;     // [0, BS*EE)
    int b = idx >> 16;
    int e = idx & (EE - 1);
    const int* base = coo + (size_t)b * 2 * EE;
    int src = base[e] & (M - 1);
    int tgt = base[EE + e] & (M - 1);
    atomicOr(&bits[(size_t)(b * M + src) * WPR + (tgt >> 5)], 1u << (tgt & 31));
}

// One 32-lane group per TWO adjacent rows (lane = t = column). Each lane holds
// 4 bitmap words per row (coalesced 512 B/row/group). Ballot -> group-uniform
// nonzero-word mask -> shfl word -> ffs bits -> ~16 gathers/row. The scan
// chain is register-only (no load on the critical path, unlike R4's 73us
// LDS/global word-scan).
__global__ __launch_bounds__(256) void compute_bits(const float* __restrict__ y,
                                                    const unsigned int* __restrict__ bits,
                                                    float* __restrict__ partials) {
    __shared__ float wsum[4];
    const int tid = threadIdx.x;
    const int t = tid & 31;                        // column t
    const int grp = tid >> 5;                      // 8 groups/block
    const int half = grp & 1;                      // which half of the wave
    const int rowA = blockIdx.x * 16 + grp * 2;    // two adjacent rows
    const int b = rowA >> 12;                      // same batch (16-aligned)
    const int iA = rowA & (M - 1);
    const int iB = iA + 1;

    const float* yb = y + (size_t)b * M * TT;
    const unsigned int* bmA = bits + (size_t)rowA * WPR;

    unsigned int wA[4], wB[4];
    #pragma unroll
    for (int s = 0; s < 4; ++s) {
        wA[s] = bmA[s * 32 + t];                   // coalesced 128 B per segment
        wB[s] = bmA[WPR + s * 32 + t];
    }

    float accA = yb[iA * TT + t];                  // identity (eye) terms
    float accB = yb[iB * TT + t];
    float ynA = (t < 31) ? yb[iA * TT + t + 1] : 0.0f;
    float ynB = (t < 31) ? yb[iB * TT + t + 1] : 0.0f;

    #pragma unroll
    for (int s = 0; s < 4; ++s) {
        unsigned int mA = (unsigned int)(__ballot(wA[s] != 0u) >> (half ? 32 : 0));
        unsigned int mB = (unsigned int)(__ballot(wB[s] != 0u) >> (half ? 32 : 0));
        while (mA) {
            int k = __ffs(mA) - 1; mA &= mA - 1;
            unsigned int w = __shfl(wA[s], k, 32);     // the nonzero word
            int jbase = (s * 32 + k) * 32;
            while (w) { int bit = __ffs(w) - 1; w &= w - 1;
                        accA += yb[(jbase + bit) * TT + t]; }
        }
        while (mB) {
            int k = __ffs(mB) - 1; mB &= mB - 1;
            unsigned int w = __shfl(wB[s], k, 32);
            int jbase = (s * 32 + k) * 32;
            while (w) { int bit = __ffs(w) - 1; w &= w - 1;
                        accB += yb[(jbase + bit) * TT + t]; }
        }
    }

    float v = 0.0f;
    if (t < 31) v = fmaxf(ynA - accA, 0.0f) + fmaxf(ynB - accB, 0.0f);
    #pragma unroll
    for (int off = 32; off; off >>= 1) v += __shfl_down(v, off, 64);

    if ((tid & 63) == 0) wsum[tid >> 6] = v;
    __syncthreads();
    if (tid == 0) partials[blockIdx.x] = wsum[0] + wsum[1] + wsum[2] + wsum[3];
}

// Single block sums the 2048 partials. No atomics anywhere.
__global__ __launch_bounds__(1024) void reduce_partials(const float* __restrict__ p,
                                                        float* __restrict__ out) {
    const int tid = threadIdx.x;
    float s = 0.0f;
    for (int k = tid; k < NBLK; k += 1024) s += p[k];
    #pragma unroll
    for (int off = 32; off; off >>= 1) s += __shfl_down(s, off, 64);
    __shared__ float ws[16];
    if ((tid & 63) == 0) ws[tid >> 6] = s;
    __syncthreads();
    if (tid == 0) {
        float tot = 0.0f;
        #pragma unroll
        for (int k = 0; k < 16; ++k) tot += ws[k];
        out[0] = tot;
    }
}

// ---------------- Fallback (R3): LDS bitmap, no scratch ----------------
#define ROWS   64
#define NCHUNK (M / ROWS)

__global__ __launch_bounds__(256) void nil_reg_lds(const float* __restrict__ y,
                                                   const int* __restrict__ coo,
                                                   float* __restrict__ out) {
    __shared__ unsigned int bm[ROWS * WPR];
    const int tid = threadIdx.x;
    const int b = blockIdx.x / NCHUNK;
    const int chunk = blockIdx.x % NCHUNK;
    const int row0 = chunk * ROWS;
    for (int i = tid; i < ROWS * WPR; i += 256) bm[i] = 0;
    __syncthreads();
    const int* base = coo + (size_t)b * 2 * EE;
    for (int e = tid; e < EE; e += 256) {
        int src = base[e] & (M - 1);
        int tgt = base[EE + e] & (M - 1);
        int r = src - row0;
        if ((unsigned)r < (unsigned)ROWS)
            atomicOr(&bm[r * WPR + (tgt >> 5)], 1u << (tgt & 31));
    }
    __syncthreads();
    const float* yb = y + (size_t)b * M * TT;
    const int t = tid & 31;
    const int grp = tid >> 5;
    float total = 0.0f;
    for (int r = grp; r < ROWS; r += 8) {
        int i = row0 + r;
        float acc = yb[i * TT + t];
        float ynext = (t < 31) ? yb[i * TT + t + 1] : 0.0f;
        const uint4* rwp = (const uint4*)&bm[r * WPR];
        for (int w4 = 0; w4 < WPR / 4; ++w4) {
            uint4 bw = rwp[w4];
            int jb = w4 * 128;
            unsigned int w;
            w = bw.x; while (w) { int j = __ffs(w) - 1; w &= w - 1; acc += yb[(jb +      j) * TT + t]; }
            w = bw.y; while (w) { int j = __ffs(w) - 1; w &= w - 1; acc += yb[(jb + 32 + j) * TT + t]; }
            w = bw.z; while (w) { int j = __ffs(w) - 1; w &= w - 1; acc += yb[(jb + 64 + j) * TT + t]; }
            w = bw.w; while (w) { int j = __ffs(w) - 1; w &= w - 1; acc += yb[(jb + 96 + j) * TT + t]; }
        }
        if (t < 31) total += fmaxf(ynext - acc, 0.0f);
    }
    #pragma unroll
    for (int off = 32; off; off >>= 1) total += __shfl_down(total, off, 64);
    if ((tid & 63) == 0) atomicAdd(out, total);
}

extern "C" void kernel_launch(void* const* d_in, const int* in_sizes, int n_in,
                              void* d_out, int out_size, void* d_ws, size_t ws_size,
                              hipStream_t stream) {
    const float* y = (const float*)d_in[0];     // (BS*M, TT) f32
    const int* coo = (const int*)d_in[1];       // (BS, 2, EE) delivered as int32
    float* out = (float*)d_out;

    if (ws_size >= WS_NEED) {
        char* ws = (char*)d_ws;
        unsigned int* bits = (unsigned int*)ws;
        float* partials = (float*)(ws + BITS_BYTES);
        hipMemsetAsync(bits, 0, BITS_BYTES, stream);   // init + atomic warm (mandatory)
        build_bits<<<(BS * EE) / 256, 256, 0, stream>>>(coo, bits);
        compute_bits<<<NBLK, 256, 0, stream>>>(y, bits, partials);
        reduce_partials<<<1, 1024, 0, stream>>>(partials, out);
    } else {
        hipMemsetAsync(out, 0, sizeof(float), stream);
        nil_reg_lds<<<BS * NCHUNK, 256, 0, stream>>>(y, coo, out);
    }
}